// Round 1
// baseline (250.449 us; speedup 1.0000x reference)
//
#include <hip/hip_runtime.h>
#include <hip/hip_bf16.h>

#define B_   32
#define L_   2048
#define CIN  256
#define HID  512
#define TL   64
#define NLT  (L_ / TL)   // 32 l-tiles per batch

typedef __bf16 bf16_t;
typedef __bf16 bf16x8 __attribute__((ext_vector_type(8)));
typedef __bf16 bf16x4 __attribute__((ext_vector_type(4)));
typedef float  f32x4  __attribute__((ext_vector_type(4)));

__device__ __forceinline__ float fast_tanh(float v) {
    // tanh(x) = (e^{2x}-1)/(e^{2x}+1); clamp so e never overflows.
    float x = fminf(fmaxf(v, -9.0f), 9.0f);
    float e = exp2f(x * 2.885390081777927f);           // e^{2x}
    return (e - 1.0f) * __builtin_amdgcn_rcpf(e + 1.0f);
}

// ---------------------------------------------------------------------------
// Kernel 1: cast weights fp32 -> bf16 into workspace
// ---------------------------------------------------------------------------
__global__ void cast_weights_kernel(const float* __restrict__ W1, const float* __restrict__ W2,
                                    bf16_t* __restrict__ W1b, bf16_t* __restrict__ W2b)
{
    int i = blockIdx.x * blockDim.x + threadIdx.x;
    if (i < HID * CIN) W1b[i] = (bf16_t)W1[i];
    if (i < HID * HID) W2b[i] = (bf16_t)W2[i];
}

// ---------------------------------------------------------------------------
// Kernel 2: fused project(x), project(y), tanh*tanh, partial row-reduction.
// Block = (batch b, 64-row L-tile). 512 threads = 8 waves; wave w owns
// output cols [w*64, w*64+64). MFMA 16x16x32 bf16.
// ---------------------------------------------------------------------------
__global__ __launch_bounds__(512, 2)
void fused_proj_kernel(const float* __restrict__ x, const float* __restrict__ y,
                       const bf16_t* __restrict__ W1b, const float* __restrict__ b1,
                       const bf16_t* __restrict__ W2b, const float* __restrict__ b2,
                       float* __restrict__ partial)
{
    __shared__ bf16_t A_lds[TL * CIN];   // 32 KB input tile (bf16, swizzled)
    __shared__ bf16_t H_lds[TL * HID];   // 64 KB hidden tile (bf16, swizzled)

    const int tid  = threadIdx.x;
    const int lane = tid & 63;
    const int wv   = tid >> 6;           // wave 0..7
    const int l15  = lane & 15;
    const int l4   = lane >> 4;
    const int blk  = blockIdx.x;
    const int b    = blk >> 5;           // batch
    const int lt   = blk & 31;           // l-tile
    const int col0 = wv * 64;            // this wave's output-col base

    const float* xrows = x + ((size_t)(b * L_) + (size_t)lt * TL) * CIN;
    const float* yrows = y + ((size_t)(b * L_) + (size_t)lt * TL) * CIN;

    float bias1[4], bias2[4];
#pragma unroll
    for (int j = 0; j < 4; ++j) {
        bias1[j] = b1[col0 + j * 16 + l15];
        bias2[j] = b2[col0 + j * 16 + l15];
    }

    // --- stage a [TL x CIN] fp32 tile -> bf16 into A_lds (XOR-swizzled rows)
    auto stage = [&](const float* src) {
        const int r = tid >> 3;          // 64 rows, 8 threads per row
        const int q = tid & 7;
        const float4* srow = reinterpret_cast<const float4*>(src + (size_t)r * CIN);
        char* rowp = (char*)A_lds + r * (CIN * 2);
        const unsigned swz = (unsigned)((r & 7) << 4);
#pragma unroll
        for (int c = 0; c < 8; ++c) {
            const int f = q + 8 * c;     // float4 index within row (coalesced)
            float4 v = srow[f];
            bf16x4 h;
            h[0] = (bf16_t)v.x; h[1] = (bf16_t)v.y; h[2] = (bf16_t)v.z; h[3] = (bf16_t)v.w;
            *reinterpret_cast<bf16x4*>(rowp + (((unsigned)(8 * f)) ^ swz)) = h;
        }
    };

    // --- GEMM1: [TL x CIN](LDS) x W1b[HID x CIN] -> acc (fp32 frags)
    auto gemm1 = [&](f32x4 (&acc)[4][4]) {
#pragma unroll
        for (int i = 0; i < 4; ++i)
#pragma unroll
            for (int j = 0; j < 4; ++j) acc[i][j] = (f32x4){0.f, 0.f, 0.f, 0.f};
        for (int kk = 0; kk < CIN / 32; ++kk) {
            bf16x8 a[4], w[4];
#pragma unroll
            for (int i = 0; i < 4; ++i) {
                int r = i * 16 + l15;
                unsigned off = (unsigned)(r * (CIN * 2)) +
                               (((unsigned)(kk * 64 + l4 * 16)) ^ ((unsigned)((r & 7) << 4)));
                a[i] = *reinterpret_cast<const bf16x8*>((const char*)A_lds + off);
            }
#pragma unroll
            for (int j = 0; j < 4; ++j) {
                int cc = col0 + j * 16 + l15;
                w[j] = *reinterpret_cast<const bf16x8*>(W1b + (size_t)cc * CIN + kk * 32 + l4 * 8);
            }
#pragma unroll
            for (int i = 0; i < 4; ++i)
#pragma unroll
                for (int j = 0; j < 4; ++j)
                    acc[i][j] = __builtin_amdgcn_mfma_f32_16x16x32_bf16(a[i], w[j], acc[i][j], 0, 0, 0);
        }
    };

    // --- write H1 = acc + b1 as bf16 into H_lds (XOR-swizzled)
    auto writeH = [&](f32x4 (&acc)[4][4]) {
#pragma unroll
        for (int i = 0; i < 4; ++i)
#pragma unroll
            for (int j = 0; j < 4; ++j) {
                unsigned colb = (unsigned)((col0 + j * 16 + l15) * 2);
#pragma unroll
                for (int r2 = 0; r2 < 4; ++r2) {
                    int r = i * 16 + l4 * 4 + r2;
                    float v = acc[i][j][r2] + bias1[j];
                    *reinterpret_cast<bf16_t*>((char*)H_lds + r * (HID * 2) +
                                               (colb ^ ((unsigned)((r & 7) << 4)))) = (bf16_t)v;
                }
            }
    };

    // --- GEMM2: [TL x HID](LDS) x W2b[HID x HID] -> acc
    auto gemm2 = [&](f32x4 (&acc)[4][4]) {
#pragma unroll
        for (int i = 0; i < 4; ++i)
#pragma unroll
            for (int j = 0; j < 4; ++j) acc[i][j] = (f32x4){0.f, 0.f, 0.f, 0.f};
        for (int kk = 0; kk < HID / 32; ++kk) {
            bf16x8 a[4], w[4];
#pragma unroll
            for (int i = 0; i < 4; ++i) {
                int r = i * 16 + l15;
                unsigned off = (unsigned)(r * (HID * 2)) +
                               (((unsigned)(kk * 64 + l4 * 16)) ^ ((unsigned)((r & 7) << 4)));
                a[i] = *reinterpret_cast<const bf16x8*>((const char*)H_lds + off);
            }
#pragma unroll
            for (int j = 0; j < 4; ++j) {
                int cc = col0 + j * 16 + l15;
                w[j] = *reinterpret_cast<const bf16x8*>(W2b + (size_t)cc * HID + kk * 32 + l4 * 8);
            }
#pragma unroll
            for (int i = 0; i < 4; ++i)
#pragma unroll
                for (int j = 0; j < 4; ++j)
                    acc[i][j] = __builtin_amdgcn_mfma_f32_16x16x32_bf16(a[i], w[j], acc[i][j], 0, 0, 0);
        }
    };

    f32x4 acc[4][4];
    f32x4 tx[4][4];

    // ---- x pipeline
    stage(xrows);
    __syncthreads();                 // A_lds(x) ready
    gemm1(acc);
    writeH(acc);
    __syncthreads();                 // H_lds(x) ready; all A_lds(x) reads done
    stage(yrows);                    // overlap-ish: overwrite A_lds with y
    gemm2(acc);                      // reads H_lds(x), W2
#pragma unroll
    for (int i = 0; i < 4; ++i)
#pragma unroll
        for (int j = 0; j < 4; ++j)
#pragma unroll
            for (int r2 = 0; r2 < 4; ++r2)
                tx[i][j][r2] = fast_tanh(acc[i][j][r2] + bias2[j]);
    __syncthreads();                 // all H_lds(x) reads + A_lds(y) writes done

    // ---- y pipeline
    gemm1(acc);
    writeH(acc);
    __syncthreads();                 // H_lds(y) ready
    gemm2(acc);

    // ---- product + reduce over the tile's 64 rows
    float colsum[4] = {0.f, 0.f, 0.f, 0.f};
#pragma unroll
    for (int i = 0; i < 4; ++i)
#pragma unroll
        for (int j = 0; j < 4; ++j)
#pragma unroll
            for (int r2 = 0; r2 < 4; ++r2) {
                float ty = fast_tanh(acc[i][j][r2] + bias2[j]);
                colsum[j] += tx[i][j][r2] * ty;
            }
    // rows live in (l4, reg): sum across the four 16-lane groups
#pragma unroll
    for (int j = 0; j < 4; ++j) {
        colsum[j] += __shfl_xor(colsum[j], 16);
        colsum[j] += __shfl_xor(colsum[j], 32);
    }
    if (lane < 16) {
#pragma unroll
        for (int j = 0; j < 4; ++j)
            partial[(size_t)blk * HID + col0 + j * 16 + lane] = colsum[j];
    }
}

// ---------------------------------------------------------------------------
// Kernel 3: sum the 32 l-tile partials per batch -> out[B][HID]
// ---------------------------------------------------------------------------
__global__ void reduce_kernel(const float* __restrict__ partial, float* __restrict__ out)
{
    int b = blockIdx.x;
    int g = threadIdx.x;             // 512 threads
    float s = 0.f;
#pragma unroll
    for (int t = 0; t < NLT; ++t)
        s += partial[((size_t)(b * NLT + t)) * HID + g];
    out[b * HID + g] = s;
}

extern "C" void kernel_launch(void* const* d_in, const int* in_sizes, int n_in,
                              void* d_out, int out_size, void* d_ws, size_t ws_size,
                              hipStream_t stream)
{
    const float* x  = (const float*)d_in[0];
    const float* y  = (const float*)d_in[1];
    const float* W1 = (const float*)d_in[2];
    const float* b1 = (const float*)d_in[3];
    const float* W2 = (const float*)d_in[4];
    const float* b2 = (const float*)d_in[5];
    float* out = (float*)d_out;

    char* ws = (char*)d_ws;
    bf16_t* W1b    = (bf16_t*)ws;                    // 256 KB
    bf16_t* W2b    = (bf16_t*)(ws + (256 << 10));    // 512 KB
    float*  partial = (float*)(ws + (768 << 10));    // 2 MB (1024 blocks x 512)

    hipLaunchKernelGGL(cast_weights_kernel, dim3(1024), dim3(256), 0, stream, W1, W2, W1b, W2b);
    hipLaunchKernelGGL(fused_proj_kernel, dim3(B_ * NLT), dim3(512), 0, stream,
                       x, y, W1b, b1, W2b, b2, partial);
    hipLaunchKernelGGL(reduce_kernel, dim3(B_), dim3(512), 0, stream, partial, out);
}